// Round 1
// baseline (482.639 us; speedup 1.0000x reference)
//
#include <hip/hip_runtime.h>
#include <math.h>

#define HID 32
#define HOR 12

__device__ __forceinline__ float sigmoidf_(float x) { return 1.0f / (1.0f + expf(-x)); }

// deg[src] += w
__global__ void k_deg(const int* __restrict__ src, const float* __restrict__ w,
                      float* __restrict__ deg, int E) {
    int e = blockIdx.x * 256 + threadIdx.x;
    if (e < E) atomicAdd(&deg[src[e]], w[e]);
}

// deg -> dinv in place
__global__ void k_dinv(float* __restrict__ deg, int N) {
    int n = blockIdx.x * 256 + threadIdx.x;
    if (n < N) { float d = deg[n]; deg[n] = (d > 0.0f) ? rsqrtf(d) : 0.0f; }
}

// nw[e] = -dinv[src]*w*dinv[dst]
__global__ void k_nw(const int* __restrict__ src, const int* __restrict__ dst,
                     const float* __restrict__ w, const float* __restrict__ dinv,
                     float* __restrict__ nw, int E) {
    int e = blockIdx.x * 256 + threadIdx.x;
    if (e < E) nw[e] = -dinv[src[e]] * w[e] * dinv[dst[e]];
}

// LX[dst,f] += nw*X[src,f];  LH[dst,f] += nw*H0[src,f]
// one thread per (edge, feature); zero contributions skip the atomic entirely
// (exact semantics: adding 0 is a no-op; h0==0 in practice so LH atomics vanish)
__global__ void k_scatter(const int* __restrict__ src, const int* __restrict__ dst,
                          const float* __restrict__ nw, const float* __restrict__ X,
                          const float* __restrict__ H0,
                          float* __restrict__ LX, float* __restrict__ LH, int E) {
    int t = blockIdx.x * 256 + threadIdx.x;
    int e = t >> 5;
    int f = t & 31;
    if (e >= E) return;
    float wv = nw[e];
    int s = src[e];
    int d = dst[e];
    float xv = wv * X[(s << 5) + f];
    if (xv != 0.0f) atomicAdd(&LX[(d << 5) + f], xv);
    float hv = wv * H0[(s << 5) + f];
    if (hv != 0.0f) atomicAdd(&LH[(d << 5) + f], hv);
}

// Per (node n, out-feature j): 4 gates, each = X@Wx[g,0] + LX@Wx[g,1] + h0@Wh[g,0] + LH@Wh[g,1] + biases
// lanes 0..31 of each 32-group hold one node's j's; input rows broadcast via __shfl within the group.
__global__ __launch_bounds__(256) void k_gates(
    const float* __restrict__ X, const float* __restrict__ LX,
    const float* __restrict__ H0, const float* __restrict__ LH,
    const float* __restrict__ C0,
    const float* __restrict__ Wx, const float* __restrict__ bx,
    const float* __restrict__ Wh, const float* __restrict__ bh,
    const float* __restrict__ wc, const float* __restrict__ b,
    float* __restrict__ outH, float* __restrict__ outC, int N) {
    int tid = blockIdx.x * 256 + threadIdx.x;
    int n = tid >> 5;
    int j = tid & 31;
    if (n >= N) return;

    int base = n << 5;
    float xk  = X[base + j];
    float lxk = LX[base + j];
    float hk  = H0[base + j];
    float lhk = LH[base + j];

    float pre0 = bx[0 * HID + j] + bh[0 * HID + j] + b[0 * HID + j];
    float pre1 = bx[1 * HID + j] + bh[1 * HID + j] + b[1 * HID + j];
    float pre2 = bx[2 * HID + j] + bh[2 * HID + j] + b[2 * HID + j];
    float pre3 = bx[3 * HID + j] + bh[3 * HID + j] + b[3 * HID + j];

    #pragma unroll 8
    for (int k = 0; k < HID; ++k) {
        float xv  = __shfl(xk, k, 32);
        float lxv = __shfl(lxk, k, 32);
        float hv  = __shfl(hk, k, 32);
        float lhv = __shfl(lhk, k, 32);
        int row = k * HID + j;
        // Wx layout: (4 gates, 2 cheb, 32, 32)
        pre0 += xv * Wx[0 * 2048 + row] + lxv * Wx[0 * 2048 + 1024 + row]
              + hv * Wh[0 * 2048 + row] + lhv * Wh[0 * 2048 + 1024 + row];
        pre1 += xv * Wx[1 * 2048 + row] + lxv * Wx[1 * 2048 + 1024 + row]
              + hv * Wh[1 * 2048 + row] + lhv * Wh[1 * 2048 + 1024 + row];
        pre2 += xv * Wx[2 * 2048 + row] + lxv * Wx[2 * 2048 + 1024 + row]
              + hv * Wh[2 * 2048 + row] + lhv * Wh[2 * 2048 + 1024 + row];
        pre3 += xv * Wx[3 * 2048 + row] + lxv * Wx[3 * 2048 + 1024 + row]
              + hv * Wh[3 * 2048 + row] + lhv * Wh[3 * 2048 + 1024 + row];
    }

    float c0v = C0[base + j];
    float I  = sigmoidf_(pre0 + wc[0 * HID + j] * c0v);
    float Fg = sigmoidf_(pre1 + wc[1 * HID + j] * c0v);
    float T  = tanhf(pre2);
    float C  = Fg * c0v + I * T;
    float O  = sigmoidf_(pre3 + wc[2 * HID + j] * C);
    float H  = O * tanhf(C);

    outH[base + j] = H;
    outC[base + j] = C;
}

// h[n,t] = b_lin[t] + sum_k relu(H[n,k]) * W_lin[k,t]
__global__ void k_head(const float* __restrict__ H, const float* __restrict__ Wl,
                       const float* __restrict__ bl, float* __restrict__ hout, int N) {
    int tid = blockIdx.x * 256 + threadIdx.x;
    int n = tid / HOR;
    int t = tid - n * HOR;
    if (n >= N) return;
    float acc = bl[t];
    #pragma unroll
    for (int k = 0; k < HID; ++k) {
        float v = H[(n << 5) + k];
        acc += fmaxf(v, 0.0f) * Wl[k * HOR + t];
    }
    hout[n * HOR + t] = acc;
}

extern "C" void kernel_launch(void* const* d_in, const int* in_sizes, int n_in,
                              void* d_out, int out_size, void* d_ws, size_t ws_size,
                              hipStream_t stream) {
    const float* x  = (const float*)d_in[0];
    const int*   ei = (const int*)d_in[1];
    const float* ew = (const float*)d_in[2];
    const float* Wx = (const float*)d_in[3];
    const float* bx = (const float*)d_in[4];
    const float* Wh = (const float*)d_in[5];
    const float* bh = (const float*)d_in[6];
    const float* wc = (const float*)d_in[7];
    const float* b  = (const float*)d_in[8];
    const float* Wl = (const float*)d_in[9];
    const float* bl = (const float*)d_in[10];
    const float* h0 = (const float*)d_in[11];
    const float* c0 = (const float*)d_in[12];

    int N = in_sizes[0] / HID;      // x is (N,1,32)
    int E = in_sizes[2];            // edge_weight is (E,)
    const int* src = ei;
    const int* dst = ei + E;

    // workspace layout (floats): [deg(N, padded)] [LX(N*32)] [LH(N*32)] [nw(E)]
    float* ws = (float*)d_ws;
    size_t degN = (size_t)((N + 127) / 128) * 128;
    float* deg = ws;
    float* LX  = ws + degN;
    float* LH  = LX + (size_t)N * HID;
    float* nw  = LH + (size_t)N * HID;
    size_t zeroFloats = degN + 2 * (size_t)N * HID;

    float* hOut = (float*)d_out;            // (N,12)
    float* HOut = hOut + (size_t)N * HOR;   // (N,32)
    float* COut = HOut + (size_t)N * HID;   // (N,32)

    hipMemsetAsync(d_ws, 0, zeroFloats * sizeof(float), stream);

    k_deg<<<(E + 255) / 256, 256, 0, stream>>>(src, ew, deg, E);
    k_dinv<<<(N + 255) / 256, 256, 0, stream>>>(deg, N);
    k_nw<<<(E + 255) / 256, 256, 0, stream>>>(src, dst, ew, deg, nw, E);

    long long scatterThreads = (long long)E * HID;
    int scatterBlocks = (int)((scatterThreads + 255) / 256);
    k_scatter<<<scatterBlocks, 256, 0, stream>>>(src, dst, nw, x, h0, LX, LH, E);

    k_gates<<<(N * HID + 255) / 256, 256, 0, stream>>>(x, LX, h0, LH, c0,
                                                       Wx, bx, Wh, bh, wc, b,
                                                       HOut, COut, N);

    k_head<<<(N * HOR + 255) / 256, 256, 0, stream>>>(HOut, Wl, bl, hOut, N);
}

// Round 2
// 477.593 us; speedup vs baseline: 1.0106x; 1.0106x over previous
//
#include <hip/hip_runtime.h>
#include <math.h>

#define HID 32
#define HOR 12

__device__ __forceinline__ float sigmoidf_(float x) { return 1.0f / (1.0f + expf(-x)); }

// per-edge: deg[src] += w (float atomic), cnt[dst] += 1 (int atomic)
__global__ void k_deg_cnt(const int* __restrict__ src, const int* __restrict__ dst,
                          const float* __restrict__ w, float* __restrict__ deg,
                          int* __restrict__ cnt, int E) {
    int e = blockIdx.x * 256 + threadIdx.x;
    if (e < E) {
        atomicAdd(&deg[src[e]], w[e]);
        atomicAdd(&cnt[dst[e]], 1);
    }
}

// deg -> dinv in place
__global__ void k_dinv(float* __restrict__ deg, int N) {
    int n = blockIdx.x * 256 + threadIdx.x;
    if (n < N) { float d = deg[n]; deg[n] = (d > 0.0f) ? rsqrtf(d) : 0.0f; }
}

// flag = 1 if any h0 element nonzero (lets gather skip the H0 pass when h0==0)
__global__ void k_hflag(const float* __restrict__ h0, int* __restrict__ flag, int total) {
    int i = blockIdx.x * 256 + threadIdx.x;
    float v = (i < total) ? h0[i] : 0.0f;
    if (__ballot(v != 0.0f)) {
        if ((threadIdx.x & 63) == 0) atomicOr(flag, 1);
    }
}

// scan pass A: per-block sums of cnt
__global__ void k_scan_blocksum(const int* __restrict__ cnt, int* __restrict__ bsum, int N) {
    __shared__ int s[256];
    int i = blockIdx.x * 256 + threadIdx.x;
    s[threadIdx.x] = (i < N) ? cnt[i] : 0;
    __syncthreads();
    for (int off = 128; off > 0; off >>= 1) {
        if (threadIdx.x < off) s[threadIdx.x] += s[threadIdx.x + off];
        __syncthreads();
    }
    if (threadIdx.x == 0) bsum[blockIdx.x] = s[0];
}

// scan pass B: exclusive scan of block sums in place (single block; nB <= 256)
__global__ void k_scan_top(int* __restrict__ bsum, int nB) {
    __shared__ int s[256];
    int tid = threadIdx.x;
    int v = (tid < nB) ? bsum[tid] : 0;
    s[tid] = v;
    __syncthreads();
    for (int off = 1; off < 256; off <<= 1) {
        int t = (tid >= off) ? s[tid - off] : 0;
        __syncthreads();
        s[tid] += t;
        __syncthreads();
    }
    if (tid < nB) bsum[tid] = s[tid] - v;  // exclusive
}

// scan pass C: per-block exclusive scan + block offset -> rowptr, cursor
__global__ void k_scan_final(const int* __restrict__ cnt, const int* __restrict__ bsum,
                             int* __restrict__ rowptr, int* __restrict__ cursor, int N) {
    __shared__ int s[256];
    int tid = threadIdx.x;
    int i = blockIdx.x * 256 + tid;
    int v = (i < N) ? cnt[i] : 0;
    s[tid] = v;
    __syncthreads();
    for (int off = 1; off < 256; off <<= 1) {
        int t = (tid >= off) ? s[tid - off] : 0;
        __syncthreads();
        s[tid] += t;
        __syncthreads();
    }
    int excl = s[tid] - v + bsum[blockIdx.x];
    if (i < N) {
        rowptr[i] = excl;
        cursor[i] = excl;
        if (i == N - 1) rowptr[N] = excl + v;
    }
}

// bin edges by dst; pack (src, nw) into int2
__global__ void k_fill(const int* __restrict__ src, const int* __restrict__ dst,
                       const float* __restrict__ w, const float* __restrict__ dinv,
                       int* __restrict__ cursor, int2* __restrict__ epair, int E) {
    int e = blockIdx.x * 256 + threadIdx.x;
    if (e >= E) return;
    int s = src[e], d = dst[e];
    float nw = -dinv[s] * w[e] * dinv[d];
    int p = atomicAdd(&cursor[d], 1);
    epair[p] = make_int2(s, __float_as_int(nw));
}

// per dst node (32 lanes = 32 feats): accumulate LX (and LH if hflag) without atomics
__global__ __launch_bounds__(256) void k_gather(const int* __restrict__ rowptr,
                                                const int2* __restrict__ epair,
                                                const float* __restrict__ X,
                                                const float* __restrict__ H0,
                                                const int* __restrict__ hflag,
                                                float* __restrict__ LX, float* __restrict__ LH,
                                                int N) {
    int tid = blockIdx.x * 256 + threadIdx.x;
    int n = tid >> 5;
    int f = tid & 31;
    if (n >= N) return;
    int beg = rowptr[n], end = rowptr[n + 1];
    float acc = 0.0f, accH = 0.0f;
    if (*hflag) {
        #pragma unroll 4
        for (int i = beg; i < end; ++i) {
            int2 p = epair[i];
            float w = __int_as_float(p.y);
            acc  += w * X[(p.x << 5) + f];
            accH += w * H0[(p.x << 5) + f];
        }
    } else {
        #pragma unroll 4
        for (int i = beg; i < end; ++i) {
            int2 p = epair[i];
            acc += __int_as_float(p.y) * X[(p.x << 5) + f];
        }
    }
    LX[(n << 5) + f] = acc;
    LH[(n << 5) + f] = accH;
}

// Per (node n, out-feature j): 4 gates fused LSTM cell
__global__ __launch_bounds__(256) void k_gates(
    const float* __restrict__ X, const float* __restrict__ LX,
    const float* __restrict__ H0, const float* __restrict__ LH,
    const float* __restrict__ C0,
    const float* __restrict__ Wx, const float* __restrict__ bx,
    const float* __restrict__ Wh, const float* __restrict__ bh,
    const float* __restrict__ wc, const float* __restrict__ b,
    float* __restrict__ outH, float* __restrict__ outC, int N) {
    int tid = blockIdx.x * 256 + threadIdx.x;
    int n = tid >> 5;
    int j = tid & 31;
    if (n >= N) return;

    int base = n << 5;
    float xk  = X[base + j];
    float lxk = LX[base + j];
    float hk  = H0[base + j];
    float lhk = LH[base + j];

    float pre0 = bx[0 * HID + j] + bh[0 * HID + j] + b[0 * HID + j];
    float pre1 = bx[1 * HID + j] + bh[1 * HID + j] + b[1 * HID + j];
    float pre2 = bx[2 * HID + j] + bh[2 * HID + j] + b[2 * HID + j];
    float pre3 = bx[3 * HID + j] + bh[3 * HID + j] + b[3 * HID + j];

    #pragma unroll 8
    for (int k = 0; k < HID; ++k) {
        float xv  = __shfl(xk, k, 32);
        float lxv = __shfl(lxk, k, 32);
        float hv  = __shfl(hk, k, 32);
        float lhv = __shfl(lhk, k, 32);
        int row = k * HID + j;
        pre0 += xv * Wx[0 * 2048 + row] + lxv * Wx[0 * 2048 + 1024 + row]
              + hv * Wh[0 * 2048 + row] + lhv * Wh[0 * 2048 + 1024 + row];
        pre1 += xv * Wx[1 * 2048 + row] + lxv * Wx[1 * 2048 + 1024 + row]
              + hv * Wh[1 * 2048 + row] + lhv * Wh[1 * 2048 + 1024 + row];
        pre2 += xv * Wx[2 * 2048 + row] + lxv * Wx[2 * 2048 + 1024 + row]
              + hv * Wh[2 * 2048 + row] + lhv * Wh[2 * 2048 + 1024 + row];
        pre3 += xv * Wx[3 * 2048 + row] + lxv * Wx[3 * 2048 + 1024 + row]
              + hv * Wh[3 * 2048 + row] + lhv * Wh[3 * 2048 + 1024 + row];
    }

    float c0v = C0[base + j];
    float I  = sigmoidf_(pre0 + wc[0 * HID + j] * c0v);
    float Fg = sigmoidf_(pre1 + wc[1 * HID + j] * c0v);
    float T  = tanhf(pre2);
    float C  = Fg * c0v + I * T;
    float O  = sigmoidf_(pre3 + wc[2 * HID + j] * C);
    float H  = O * tanhf(C);

    outH[base + j] = H;
    outC[base + j] = C;
}

// h[n,t] = b_lin[t] + sum_k relu(H[n,k]) * W_lin[k,t]
__global__ void k_head(const float* __restrict__ H, const float* __restrict__ Wl,
                       const float* __restrict__ bl, float* __restrict__ hout, int N) {
    int tid = blockIdx.x * 256 + threadIdx.x;
    int n = tid / HOR;
    int t = tid - n * HOR;
    if (n >= N) return;
    float acc = bl[t];
    #pragma unroll
    for (int k = 0; k < HID; ++k) {
        float v = H[(n << 5) + k];
        acc += fmaxf(v, 0.0f) * Wl[k * HOR + t];
    }
    hout[n * HOR + t] = acc;
}

extern "C" void kernel_launch(void* const* d_in, const int* in_sizes, int n_in,
                              void* d_out, int out_size, void* d_ws, size_t ws_size,
                              hipStream_t stream) {
    const float* x  = (const float*)d_in[0];
    const int*   ei = (const int*)d_in[1];
    const float* ew = (const float*)d_in[2];
    const float* Wx = (const float*)d_in[3];
    const float* bx = (const float*)d_in[4];
    const float* Wh = (const float*)d_in[5];
    const float* bh = (const float*)d_in[6];
    const float* wc = (const float*)d_in[7];
    const float* b  = (const float*)d_in[8];
    const float* Wl = (const float*)d_in[9];
    const float* bl = (const float*)d_in[10];
    const float* h0 = (const float*)d_in[11];
    const float* c0 = (const float*)d_in[12];

    int N = in_sizes[0] / HID;      // x is (N,1,32)
    int E = in_sizes[2];            // edge_weight is (E,)
    const int* src = ei;
    const int* dst = ei + E;
    int nB = (N + 255) / 256;       // 196 for N=50000; must be <= 256

    // workspace layout (4-byte units), epair first for 8-byte alignment:
    // [epair 2E][LX N*32][LH N*32][rowptr N+1][cursor N][bsum 256][deg N][cnt N][flag 1]
    int* wsi = (int*)d_ws;
    int2*  epair  = (int2*)wsi;
    float* LX     = (float*)(wsi + 2 * (size_t)E);
    float* LH     = LX + (size_t)N * HID;
    int*   rowptr = (int*)(LH + (size_t)N * HID);
    int*   cursor = rowptr + (N + 1);
    int*   bsum   = cursor + N;
    float* deg    = (float*)(bsum + 256);
    int*   cnt    = (int*)(deg + N);
    int*   flag   = cnt + N;

    float* hOut = (float*)d_out;            // (N,12)
    float* HOut = hOut + (size_t)N * HOR;   // (N,32)
    float* COut = HOut + (size_t)N * HID;   // (N,32)

    // zero: deg, cnt, flag (contiguous)
    hipMemsetAsync(deg, 0, (2 * (size_t)N + 1) * sizeof(float), stream);

    k_deg_cnt<<<(E + 255) / 256, 256, 0, stream>>>(src, dst, ew, deg, cnt, E);
    k_dinv<<<(N + 255) / 256, 256, 0, stream>>>(deg, N);
    k_hflag<<<(N * HID + 255) / 256, 256, 0, stream>>>(h0, flag, N * HID);

    k_scan_blocksum<<<nB, 256, 0, stream>>>(cnt, bsum, N);
    k_scan_top<<<1, 256, 0, stream>>>(bsum, nB);
    k_scan_final<<<nB, 256, 0, stream>>>(cnt, bsum, rowptr, cursor, N);

    k_fill<<<(E + 255) / 256, 256, 0, stream>>>(src, dst, ew, deg, cursor, epair, E);

    k_gather<<<(N * HID + 255) / 256, 256, 0, stream>>>(rowptr, epair, x, h0, flag, LX, LH, N);

    k_gates<<<(N * HID + 255) / 256, 256, 0, stream>>>(x, LX, h0, LH, c0,
                                                       Wx, bx, Wh, bh, wc, b,
                                                       HOut, COut, N);

    k_head<<<(N * HOR + 255) / 256, 256, 0, stream>>>(HOut, Wl, bl, hOut, N);
}

// Round 3
// 471.211 us; speedup vs baseline: 1.0243x; 1.0135x over previous
//
#include <hip/hip_runtime.h>
#include <math.h>

#define HID 32
#define HOR 12
#define REP 16   // privatization factor for contended atomics

__device__ __forceinline__ float sigmoidf_(float x) { return 1.0f / (1.0f + expf(-x)); }

// per-edge: degR[rep][src] += w, cntR[rep][dst] += 1   (replica-major planes)
__global__ void k_deg_cnt(const int* __restrict__ src, const int* __restrict__ dst,
                          const float* __restrict__ w, float* __restrict__ degR,
                          int* __restrict__ cntR, int E, int N) {
    int e = blockIdx.x * 256 + threadIdx.x;
    if (e < E) {
        int rep = threadIdx.x & (REP - 1);
        atomicAdd(&degR[(size_t)rep * N + src[e]], w[e]);
        atomicAdd(&cntR[(size_t)rep * N + dst[e]], 1);
    }
}

// fold replica planes: dinv[n] = rsqrt(sum_r degR[r][n]); cnt[n] = sum_r cntR[r][n]
__global__ void k_fold(const float* __restrict__ degR, const int* __restrict__ cntR,
                       float* __restrict__ dinv, int* __restrict__ cnt, int N) {
    int n = blockIdx.x * 256 + threadIdx.x;
    if (n >= N) return;
    float s = 0.0f;
    int c = 0;
    #pragma unroll
    for (int r = 0; r < REP; ++r) {
        s += degR[(size_t)r * N + n];   // coalesced per plane
        c += cntR[(size_t)r * N + n];
    }
    dinv[n] = (s > 0.0f) ? rsqrtf(s) : 0.0f;
    cnt[n] = c;
}

// flag = 1 if any h0 element nonzero (lets gather skip the H0 pass when h0==0)
__global__ void k_hflag(const float* __restrict__ h0, int* __restrict__ flag, int total) {
    int i = blockIdx.x * 256 + threadIdx.x;
    float v = (i < total) ? h0[i] : 0.0f;
    if (__ballot(v != 0.0f)) {
        if ((threadIdx.x & 63) == 0) atomicOr(flag, 1);
    }
}

// scan pass A: per-block sums of cnt
__global__ void k_scan_blocksum(const int* __restrict__ cnt, int* __restrict__ bsum, int N) {
    __shared__ int s[256];
    int i = blockIdx.x * 256 + threadIdx.x;
    s[threadIdx.x] = (i < N) ? cnt[i] : 0;
    __syncthreads();
    for (int off = 128; off > 0; off >>= 1) {
        if (threadIdx.x < off) s[threadIdx.x] += s[threadIdx.x + off];
        __syncthreads();
    }
    if (threadIdx.x == 0) bsum[blockIdx.x] = s[0];
}

// scan pass B: exclusive scan of block sums in place (single block; nB <= 256)
__global__ void k_scan_top(int* __restrict__ bsum, int nB) {
    __shared__ int s[256];
    int tid = threadIdx.x;
    int v = (tid < nB) ? bsum[tid] : 0;
    s[tid] = v;
    __syncthreads();
    for (int off = 1; off < 256; off <<= 1) {
        int t = (tid >= off) ? s[tid - off] : 0;
        __syncthreads();
        s[tid] += t;
        __syncthreads();
    }
    if (tid < nB) bsum[tid] = s[tid] - v;  // exclusive
}

// scan pass C: per-node exclusive scan -> rowptr; init per-(node,rep) cursors
__global__ void k_scan_final(const int* __restrict__ cnt, const int* __restrict__ bsum,
                             const int* __restrict__ cntR,
                             int* __restrict__ rowptr, int* __restrict__ cursorR, int N) {
    __shared__ int s[256];
    int tid = threadIdx.x;
    int i = blockIdx.x * 256 + tid;
    int v = (i < N) ? cnt[i] : 0;
    s[tid] = v;
    __syncthreads();
    for (int off = 1; off < 256; off <<= 1) {
        int t = (tid >= off) ? s[tid - off] : 0;
        __syncthreads();
        s[tid] += t;
        __syncthreads();
    }
    int excl = s[tid] - v + bsum[blockIdx.x];
    if (i < N) {
        rowptr[i] = excl;
        int run = excl;
        #pragma unroll
        for (int r = 0; r < REP; ++r) {
            cursorR[(size_t)r * N + i] = run;     // coalesced per plane
            run += cntR[(size_t)r * N + i];
        }
        if (i == N - 1) rowptr[N] = excl + v;
    }
}

// bin edges by dst using privatized cursors; pack (src, nw) into int2
__global__ void k_fill(const int* __restrict__ src, const int* __restrict__ dst,
                       const float* __restrict__ w, const float* __restrict__ dinv,
                       int* __restrict__ cursorR, int2* __restrict__ epair, int E, int N) {
    int e = blockIdx.x * 256 + threadIdx.x;
    if (e >= E) return;
    int s = src[e], d = dst[e];
    float nw = -dinv[s] * w[e] * dinv[d];
    int rep = threadIdx.x & (REP - 1);
    int p = atomicAdd(&cursorR[(size_t)rep * N + d], 1);
    epair[p] = make_int2(s, __float_as_int(nw));
}

// per dst node (32 lanes = 32 feats): accumulate LX (and LH if hflag) without atomics
__global__ __launch_bounds__(256) void k_gather(const int* __restrict__ rowptr,
                                                const int2* __restrict__ epair,
                                                const float* __restrict__ X,
                                                const float* __restrict__ H0,
                                                const int* __restrict__ hflag,
                                                float* __restrict__ LX, float* __restrict__ LH,
                                                int N) {
    int tid = blockIdx.x * 256 + threadIdx.x;
    int n = tid >> 5;
    int f = tid & 31;
    if (n >= N) return;
    int beg = rowptr[n], end = rowptr[n + 1];
    float acc = 0.0f, accH = 0.0f;
    if (*hflag) {
        #pragma unroll 4
        for (int i = beg; i < end; ++i) {
            int2 p = epair[i];
            float w = __int_as_float(p.y);
            acc  += w * X[(p.x << 5) + f];
            accH += w * H0[(p.x << 5) + f];
        }
    } else {
        #pragma unroll 4
        for (int i = beg; i < end; ++i) {
            int2 p = epair[i];
            acc += __int_as_float(p.y) * X[(p.x << 5) + f];
        }
    }
    LX[(n << 5) + f] = acc;
    LH[(n << 5) + f] = accH;
}

// Per (node n, out-feature j): 4 gates fused LSTM cell
__global__ __launch_bounds__(256) void k_gates(
    const float* __restrict__ X, const float* __restrict__ LX,
    const float* __restrict__ H0, const float* __restrict__ LH,
    const float* __restrict__ C0,
    const float* __restrict__ Wx, const float* __restrict__ bx,
    const float* __restrict__ Wh, const float* __restrict__ bh,
    const float* __restrict__ wc, const float* __restrict__ b,
    float* __restrict__ outH, float* __restrict__ outC, int N) {
    int tid = blockIdx.x * 256 + threadIdx.x;
    int n = tid >> 5;
    int j = tid & 31;
    if (n >= N) return;

    int base = n << 5;
    float xk  = X[base + j];
    float lxk = LX[base + j];
    float hk  = H0[base + j];
    float lhk = LH[base + j];

    float pre0 = bx[0 * HID + j] + bh[0 * HID + j] + b[0 * HID + j];
    float pre1 = bx[1 * HID + j] + bh[1 * HID + j] + b[1 * HID + j];
    float pre2 = bx[2 * HID + j] + bh[2 * HID + j] + b[2 * HID + j];
    float pre3 = bx[3 * HID + j] + bh[3 * HID + j] + b[3 * HID + j];

    #pragma unroll 8
    for (int k = 0; k < HID; ++k) {
        float xv  = __shfl(xk, k, 32);
        float lxv = __shfl(lxk, k, 32);
        float hv  = __shfl(hk, k, 32);
        float lhv = __shfl(lhk, k, 32);
        int row = k * HID + j;
        pre0 += xv * Wx[0 * 2048 + row] + lxv * Wx[0 * 2048 + 1024 + row]
              + hv * Wh[0 * 2048 + row] + lhv * Wh[0 * 2048 + 1024 + row];
        pre1 += xv * Wx[1 * 2048 + row] + lxv * Wx[1 * 2048 + 1024 + row]
              + hv * Wh[1 * 2048 + row] + lhv * Wh[1 * 2048 + 1024 + row];
        pre2 += xv * Wx[2 * 2048 + row] + lxv * Wx[2 * 2048 + 1024 + row]
              + hv * Wh[2 * 2048 + row] + lhv * Wh[2 * 2048 + 1024 + row];
        pre3 += xv * Wx[3 * 2048 + row] + lxv * Wx[3 * 2048 + 1024 + row]
              + hv * Wh[3 * 2048 + row] + lhv * Wh[3 * 2048 + 1024 + row];
    }

    float c0v = C0[base + j];
    float I  = sigmoidf_(pre0 + wc[0 * HID + j] * c0v);
    float Fg = sigmoidf_(pre1 + wc[1 * HID + j] * c0v);
    float T  = tanhf(pre2);
    float C  = Fg * c0v + I * T;
    float O  = sigmoidf_(pre3 + wc[2 * HID + j] * C);
    float H  = O * tanhf(C);

    outH[base + j] = H;
    outC[base + j] = C;
}

// h[n,t] = b_lin[t] + sum_k relu(H[n,k]) * W_lin[k,t]
__global__ void k_head(const float* __restrict__ H, const float* __restrict__ Wl,
                       const float* __restrict__ bl, float* __restrict__ hout, int N) {
    int tid = blockIdx.x * 256 + threadIdx.x;
    int n = tid / HOR;
    int t = tid - n * HOR;
    if (n >= N) return;
    float acc = bl[t];
    #pragma unroll
    for (int k = 0; k < HID; ++k) {
        float v = H[(n << 5) + k];
        acc += fmaxf(v, 0.0f) * Wl[k * HOR + t];
    }
    hout[n * HOR + t] = acc;
}

extern "C" void kernel_launch(void* const* d_in, const int* in_sizes, int n_in,
                              void* d_out, int out_size, void* d_ws, size_t ws_size,
                              hipStream_t stream) {
    const float* x  = (const float*)d_in[0];
    const int*   ei = (const int*)d_in[1];
    const float* ew = (const float*)d_in[2];
    const float* Wx = (const float*)d_in[3];
    const float* bx = (const float*)d_in[4];
    const float* Wh = (const float*)d_in[5];
    const float* bh = (const float*)d_in[6];
    const float* wc = (const float*)d_in[7];
    const float* b  = (const float*)d_in[8];
    const float* Wl = (const float*)d_in[9];
    const float* bl = (const float*)d_in[10];
    const float* h0 = (const float*)d_in[11];
    const float* c0 = (const float*)d_in[12];

    int N = in_sizes[0] / HID;      // x is (N,1,32)
    int E = in_sizes[2];            // edge_weight is (E,)
    const int* src = ei;
    const int* dst = ei + E;
    int nB = (N + 255) / 256;       // 196 for N=50000; must be <= 256

    // workspace (4-byte units). degR/cntR alias epair: both are dead before
    // k_fill writes epair (k_fold consumes degR, k_scan_final consumes cntR).
    // [epair 2E | degR R*N + cntR R*N aliased] [LX N*32] [LH N*32]
    // [rowptr N+1] [cursorR R*N] [bsum 256] [dinv N] [cnt N] [flag 1]
    int* wsi = (int*)d_ws;
    int2*  epair  = (int2*)wsi;
    float* degR   = (float*)wsi;                      // R*N, aliases epair
    int*   cntR   = wsi + (size_t)REP * N;            // R*N, aliases epair
    float* LX     = (float*)(wsi + 2 * (size_t)E);
    float* LH     = LX + (size_t)N * HID;
    int*   rowptr = (int*)(LH + (size_t)N * HID);
    int*   cursorR= rowptr + (N + 1);
    int*   bsum   = cursorR + (size_t)REP * N;
    float* dinv   = (float*)(bsum + 256);
    int*   cnt    = (int*)(dinv + N);
    int*   flag   = cnt + N;

    float* hOut = (float*)d_out;            // (N,12)
    float* HOut = hOut + (size_t)N * HOR;   // (N,32)
    float* COut = HOut + (size_t)N * HID;   // (N,32)

    hipMemsetAsync(degR, 0, 2 * (size_t)REP * N * sizeof(int), stream);  // degR + cntR
    hipMemsetAsync(flag, 0, sizeof(int), stream);

    k_deg_cnt<<<(E + 255) / 256, 256, 0, stream>>>(src, dst, ew, degR, cntR, E, N);
    k_fold<<<(N + 255) / 256, 256, 0, stream>>>(degR, cntR, dinv, cnt, N);
    k_hflag<<<(N * HID + 255) / 256, 256, 0, stream>>>(h0, flag, N * HID);

    k_scan_blocksum<<<nB, 256, 0, stream>>>(cnt, bsum, N);
    k_scan_top<<<1, 256, 0, stream>>>(bsum, nB);
    k_scan_final<<<nB, 256, 0, stream>>>(cnt, bsum, cntR, rowptr, cursorR, N);

    k_fill<<<(E + 255) / 256, 256, 0, stream>>>(src, dst, ew, dinv, cursorR, epair, E, N);

    k_gather<<<(N * HID + 255) / 256, 256, 0, stream>>>(rowptr, epair, x, h0, flag, LX, LH, N);

    k_gates<<<(N * HID + 255) / 256, 256, 0, stream>>>(x, LX, h0, LH, c0,
                                                       Wx, bx, Wh, bh, wc, b,
                                                       HOut, COut, N);

    k_head<<<(N * HOR + 255) / 256, 256, 0, stream>>>(HOut, Wl, bl, hOut, N);
}